// Round 11
// baseline (273.783 us; speedup 1.0000x reference)
//
#include <hip/hip_runtime.h>

#define NB     64
#define NF     4096
#define TILE   16384
#define HBLK   1024
#define DBLK   1024   // 16 waves
#define FBLK   512
#define GBLK   256
#define SBLK   256
#define FB_TILE 4096
#define STAGE_HALF 8192   // scatterC LDS staging chunk (64 KB)

#define GLOBAL_AS __attribute__((address_space(1)))
#define LDS_AS    __attribute__((address_space(3)))

// bit-exact bid (order-determining — plain divides, matches reference)
__device__ __forceinline__ int compute_bid(float px, float py, float pz,
                                           float a0x, float a0y, float a0z,
                                           float vx, float vy, float vz) {
    int ix = (int)floorf((px - a0x) / vx);
    int iy = (int)floorf((py - a0y) / vy);
    int iz = (int)floorf((pz - a0z) / vz);
    ix = min(max(ix, 0), 3);
    iy = min(max(iy, 0), 3);
    iz = min(max(iz, 0), 3);
    return ix * 16 + iy * 4 + iz;
}

// 14-bit fixed-point (8 frac bits) quantization; IDENTICAL in hist & scatterC.
__device__ __forceinline__ void quant_point(float px, float py, float pz,
        float a0x, float a0y, float a0z, float vx, float vy, float vz,
        const float* s_dn, const float* s_sc,
        int& b, int& qx, int& qy, int& qz, int& key) {
    b = compute_bid(px, py, pz, a0x, a0y, a0z, vx, vy, vz);
    float fx = (px - s_dn[3 * b])     * s_sc[3 * b];
    float fy = (py - s_dn[3 * b + 1]) * s_sc[3 * b + 1];
    float fz = (pz - s_dn[3 * b + 2]) * s_sc[3 * b + 2];
    qx = min(max(__float2int_rn(fx * 256.0f), 0), 16128);
    qy = min(max(__float2int_rn(fy * 256.0f), 0), 16128);
    qz = min(max(__float2int_rn(fz * 256.0f), 0), 16128);
    key = (b << 6) | ((qz >> 12) << 4) | ((qy >> 12) << 2) | (qx >> 12);
}

// ---- Pass 1: coarse per-tile hist (bucket-major) + global fine totals ----
__global__ void __launch_bounds__(HBLK) hist_kernel(
        const float* __restrict__ xyz, const float* __restrict__ aabb,
        const float* __restrict__ dmin, const float* __restrict__ dmax,
        int* __restrict__ hist64, int* __restrict__ tot4096, int N, int T) {
    __shared__ int   sh[NF];
    __shared__ float s_dn[192], s_sc[192];
    const int tid = threadIdx.x, g = blockIdx.x;
    for (int l = tid; l < NF; l += HBLK) sh[l] = 0;
    if (tid < 192) { s_dn[tid] = dmin[tid]; s_sc[tid] = 63.0f / (dmax[tid] - dmin[tid]); }
    const float a0x = aabb[0], a0y = aabb[1], a0z = aabb[2];
    const float vx = (aabb[3] - a0x) * 0.25f;
    const float vy = (aabb[4] - a0y) * 0.25f;
    const float vz = (aabb[5] - a0z) * 0.25f;
    __syncthreads();
    for (int c = 0; c < TILE / (HBLK * 4); ++c) {
        int p0 = g * TILE + c * (HBLK * 4) + tid * 4;
        int b, qx, qy, qz, k;
        if (p0 + 3 < N) {
            const float4* v4 = (const float4*)(xyz + (size_t)p0 * 3);
            float4 f0 = v4[0], f1 = v4[1], f2 = v4[2];
            quant_point(f0.x, f0.y, f0.z, a0x, a0y, a0z, vx, vy, vz, s_dn, s_sc, b, qx, qy, qz, k);
            atomicAdd(&sh[k], 1);
            quant_point(f0.w, f1.x, f1.y, a0x, a0y, a0z, vx, vy, vz, s_dn, s_sc, b, qx, qy, qz, k);
            atomicAdd(&sh[k], 1);
            quant_point(f1.z, f1.w, f2.x, a0x, a0y, a0z, vx, vy, vz, s_dn, s_sc, b, qx, qy, qz, k);
            atomicAdd(&sh[k], 1);
            quant_point(f2.y, f2.z, f2.w, a0x, a0y, a0z, vx, vy, vz, s_dn, s_sc, b, qx, qy, qz, k);
            atomicAdd(&sh[k], 1);
        } else {
            for (int t = 0; t < 4; ++t) {
                int i = p0 + t;
                if (i < N) {
                    quant_point(xyz[3 * i], xyz[3 * i + 1], xyz[3 * i + 2],
                                a0x, a0y, a0z, vx, vy, vz, s_dn, s_sc, b, qx, qy, qz, k);
                    atomicAdd(&sh[k], 1);
                }
            }
        }
    }
    __syncthreads();
    for (int l = tid; l < NF; l += HBLK) {
        int c = sh[l];
        if (c) atomicAdd(&tot4096[l], c);
    }
    if (tid < NB) {
        int s = 0;
        #pragma unroll
        for (int j = 0; j < 64; ++j) s += sh[tid * 64 + j];
        hist64[tid * T + g] = s;
    }
}

// ---- Pass 2: blocks 0..63 scan hist64 rows (in place, + tot64);
//      block 64 scans fine totals -> foff[0..NF], fcnt=foff ----
__global__ void scans_kernel(int* __restrict__ hist64, int* __restrict__ tot64,
                             const int* __restrict__ tot4096,
                             int* __restrict__ foff, int* __restrict__ fcnt, int G) {
    __shared__ int sh[SBLK];
    const int t = threadIdx.x;
    if (blockIdx.x < NB) {
        const int b = blockIdx.x;
        const int L = (G + SBLK - 1) / SBLK;
        const int lo = t * L;
        const int n = min(L, max(0, G - lo));
        const int base = b * G + lo;
        int s = 0;
        for (int k = 0; k < n; ++k) s += hist64[base + k];
        sh[t] = s;
        __syncthreads();
        for (int off = 1; off < SBLK; off <<= 1) {
            int v = (t >= off) ? sh[t - off] : 0;
            __syncthreads();
            sh[t] += v;
            __syncthreads();
        }
        int excl = (t == 0) ? 0 : sh[t - 1];
        for (int k = 0; k < n; ++k) {
            int v = hist64[base + k];
            hist64[base + k] = excl;
            excl += v;
        }
        if (t == SBLK - 1) tot64[b] = sh[SBLK - 1];
    } else {
        const int L = NF / SBLK;  // 16
        int loc[16];
        int s = 0;
        #pragma unroll
        for (int j = 0; j < L; ++j) { loc[j] = tot4096[t * L + j]; s += loc[j]; }
        sh[t] = s;
        __syncthreads();
        for (int o = 1; o < SBLK; o <<= 1) {
            int v = (t >= o) ? sh[t - o] : 0;
            __syncthreads();
            sh[t] += v;
            __syncthreads();
        }
        int run = (t == 0) ? 0 : sh[t - 1];
        #pragma unroll
        for (int j = 0; j < L; ++j) {
            foff[t * L + j] = run;
            fcnt[t * L + j] = run;
            run += loc[j];
        }
        if (t == SBLK - 1) foff[NF] = run;  // == N
    }
}

// ---- Pass 3: COARSE stable scatter — RECOMPUTE variant (r10).
// r10 profile: VGPR capped at 64 for 2 blocks/CU; cache[16] (32 VGPRs of
// point payload held across the kernel) starved the regalloc -> the
// 16-round load loops serialize on memory latency (23% VALU, 1.6 TB/s).
// Fix: drop the register cache. Pass A computes bid-only counts; passes
// B1/B2 re-read xyz (L2/L3-hot tile) and recompute quant + IDENTICAL
// deterministic ballot ranks, writing straight to staging LDS. s_run
// (4 KB) carries the re-accumulated per-wave run counts. LDS 76 KB,
// still 2 blocks/CU; write pattern (amp ~1 dump) unchanged. ----
__global__ void __launch_bounds__(DBLK) scatterC_kernel(
        const float* __restrict__ xyz, const float* __restrict__ aabb,
        const float* __restrict__ dmin, const float* __restrict__ dmax,
        const int* __restrict__ hist64, const int* __restrict__ tot64,
        unsigned long long* __restrict__ payloadC, int N, int T) {
    __shared__ unsigned long long stage[STAGE_HALF];   // 64 KB staging (half tile)
    __shared__ int   s_wh[16][NB];    // pass-A counts -> wave-inclusive prefix
    __shared__ int   s_run[16][NB];   // fresh run counters for B1/B2 recompute
    __shared__ int   s_cnt0[NB];
    __shared__ int   s_off[NB];
    __shared__ int   s_start[NB];   // tile-local bucket starts (exclusive)
    __shared__ int   s_gb[NB];      // global base - local start
    __shared__ float s_dn[192], s_sc[192];
    const int tid = threadIdx.x, g = blockIdx.x;
    const int lane = tid & 63, wv = tid >> 6;
    if (tid < NB) s_off[tid] = tot64[tid];
    if (tid < 192) { s_dn[tid] = dmin[tid]; s_sc[tid] = 63.0f / (dmax[tid] - dmin[tid]); }
    ((int*)s_wh)[tid] = 0;   // 16*64 == DBLK
    const float a0x = aabb[0], a0y = aabb[1], a0z = aabb[2];
    const float vx = (aabb[3] - a0x) * 0.25f;
    const float vy = (aabb[4] - a0y) * 0.25f;
    const float vz = (aabb[5] - a0z) * 0.25f;
    __syncthreads();
    for (int o = 1; o < NB; o <<= 1) {
        int v = (tid < NB && tid >= o) ? s_off[tid - o] : 0;
        __syncthreads();
        if (tid < NB) s_off[tid] += v;
        __syncthreads();
    }
    if (tid < NB) s_cnt0[tid] = hist64[tid * T + g] + (tid ? s_off[tid - 1] : 0);

    const unsigned long long lt = (1ull << lane) - 1ull;
    const int base_i = g * TILE + wv * 1024;
    // ---- pass A: bid-only per-wave bucket counts (no quant, no cache) ----
    #pragma unroll
    for (int r = 0; r < 16; ++r) {
        int i = base_i + r * 64 + lane;
        bool valid = (i < N);
        int b = 0;
        if (valid) {
            b = compute_bid(xyz[3 * i], xyz[3 * i + 1], xyz[3 * i + 2],
                            a0x, a0y, a0z, vx, vy, vz);
        }
        unsigned long long m = __ballot(valid);
        #pragma unroll
        for (int q = 0; q < 6; ++q) {
            unsigned long long bal = __ballot((b >> q) & 1);
            m &= ((b >> q) & 1) ? bal : ~bal;
        }
        int rank = __popcll(m & lt);
        int run = valid ? s_wh[wv][b] : 0;
        if (valid && rank == 0) s_wh[wv][b] = run + __popcll(m);
    }
    __syncthreads();
    // inclusive scan over the 16 waves
    for (int o = 1; o < 16; o <<= 1) {
        int v = (wv >= o) ? s_wh[wv - o][lane] : 0;
        __syncthreads();
        s_wh[wv][lane] += v;
        __syncthreads();
    }
    // exclusive scan over buckets of tile totals (wave 0, shuffle scan)
    if (wv == 0) {
        int v = s_wh[15][lane];
        int incl = v;
        #pragma unroll
        for (int o = 1; o < 64; o <<= 1) {
            int u = __shfl_up(incl, o);
            if (lane >= o) incl += u;
        }
        int excl = incl - v;
        s_start[lane] = excl;
        s_gb[lane] = s_cnt0[lane] - excl;
    }
    __syncthreads();
    const int n = min(TILE, N - g * TILE);
    // recompute pass: rebuild ranks deterministically (same xyz, same ballot
    // sequence -> bit-identical localpos), stage the selected half, in LDS.
    auto passB = [&](int half) {
        #pragma unroll
        for (int r = 0; r < 16; ++r) {
            int i = base_i + r * 64 + lane;
            bool valid = (i < N);
            int b = 0, qx = 0, qy = 0, qz = 0, key;
            if (valid) {
                quant_point(xyz[3 * i], xyz[3 * i + 1], xyz[3 * i + 2],
                            a0x, a0y, a0z, vx, vy, vz, s_dn, s_sc,
                            b, qx, qy, qz, key);
            }
            unsigned long long m = __ballot(valid);
            #pragma unroll
            for (int q = 0; q < 6; ++q) {
                unsigned long long bal = __ballot((b >> q) & 1);
                m &= ((b >> q) & 1) ? bal : ~bal;
            }
            int rank = __popcll(m & lt);
            int run = valid ? s_run[wv][b] : 0;
            if (valid && rank == 0) s_run[wv][b] = run + __popcll(m);
            if (valid) {
                int localpos = run + rank;
                int lidx = s_start[b] + (wv ? s_wh[wv - 1][b] : 0) + localpos;
                unsigned long long p48 =
                      (unsigned long long)(unsigned)qx
                    | ((unsigned long long)(unsigned)qy << 14)
                    | ((unsigned long long)(unsigned)qz << 28)
                    | ((unsigned long long)(unsigned)b  << 42);
                if (half == 0) {
                    if (lidx < STAGE_HALF) stage[lidx] = p48;
                } else {
                    if (lidx >= STAGE_HALF) stage[lidx - STAGE_HALF] = p48;
                }
            }
        }
    };
    // ---- B1: stage lidx < STAGE_HALF ----
    ((int*)s_run)[tid] = 0;
    __syncthreads();
    passB(0);
    __syncthreads();
    // dump A: j-contiguous reads -> piecewise-contiguous coalesced writes
    {
        int nA = min(n, STAGE_HALF);
        for (int j = tid; j < nA; j += DBLK) {
            unsigned long long p = stage[j];
            int b = (int)((p >> 42) & 63);
            payloadC[s_gb[b] + j] = p;
        }
    }
    __syncthreads();
    // ---- B2: stage lidx >= STAGE_HALF ----
    ((int*)s_run)[tid] = 0;
    __syncthreads();
    passB(1);
    __syncthreads();
    // dump B
    for (int j = STAGE_HALF + tid; j < n; j += DBLK) {
        unsigned long long p = stage[j - STAGE_HALF];
        int b = (int)((p >> 42) & 63);
        payloadC[s_gb[b] + j] = p;
    }
}

// ---- Pass 4: FINE scatter, fused hist+reserve+scatter on a contiguous
// coarse-sorted tile. Runs ~256/cell -> 2KB writes (amp ~1).
// 4-point batched loads: one latency exposure per 4 points. ----
__global__ void __launch_bounds__(FBLK) scatterF_kernel(
        const unsigned long long* __restrict__ payloadC,
        int* __restrict__ fcnt,
        unsigned long long* __restrict__ payloadF, int N) {
    __shared__ int s_fb[NF];  // 16 KB
    const int tid = threadIdx.x, t2 = blockIdx.x;
    for (int l = tid; l < NF; l += FBLK) s_fb[l] = 0;
    __syncthreads();
    const int lo = t2 * TILE;
    const int n = min(TILE, N - lo);
    for (int j0 = tid * 4; j0 < n; j0 += FBLK * 4) {
        unsigned long long p[4];
        int m;
        if (j0 + 3 < n) {
            m = 4;
            ulonglong2 a = *(const ulonglong2*)(payloadC + lo + j0);
            ulonglong2 b2 = *(const ulonglong2*)(payloadC + lo + j0 + 2);
            p[0] = a.x; p[1] = a.y; p[2] = b2.x; p[3] = b2.y;
        } else {
            m = n - j0;
            for (int t = 0; t < m; ++t) p[t] = payloadC[lo + j0 + t];
        }
        for (int t = 0; t < m; ++t) {
            unsigned long long pp = p[t];
            int qx = (int)(pp & 16383), qy = (int)((pp >> 14) & 16383);
            int qz = (int)((pp >> 28) & 16383), b = (int)((pp >> 42) & 63);
            int key = (b << 6) | ((qz >> 12) << 4) | ((qy >> 12) << 2) | (qx >> 12);
            atomicAdd(&s_fb[key], 1);
        }
    }
    __syncthreads();
    for (int l = tid; l < NF; l += FBLK) {
        int c = s_fb[l];
        s_fb[l] = c ? atomicAdd(&fcnt[l], c) : 0;   // reserve contiguous range
    }
    __syncthreads();
    for (int j0 = tid * 4; j0 < n; j0 += FBLK * 4) {   // L2-hot re-read
        unsigned long long p[4];
        int m;
        if (j0 + 3 < n) {
            m = 4;
            ulonglong2 a = *(const ulonglong2*)(payloadC + lo + j0);
            ulonglong2 b2 = *(const ulonglong2*)(payloadC + lo + j0 + 2);
            p[0] = a.x; p[1] = a.y; p[2] = b2.x; p[3] = b2.y;
        } else {
            m = n - j0;
            for (int t = 0; t < m; ++t) p[t] = payloadC[lo + j0 + t];
        }
        for (int t = 0; t < m; ++t) {
            unsigned long long pp = p[t];
            int qx = (int)(pp & 16383), qy = (int)((pp >> 14) & 16383);
            int qz = (int)((pp >> 28) & 16383), b = (int)((pp >> 42) & 63);
            int key = (b << 6) | ((qz >> 12) << 4) | ((qy >> 12) << 2) | (qx >> 12);
            int fpos = atomicAdd(&s_fb[key], 1);
            payloadF[fpos] = (pp & ((1ull << 42) - 1))
                           | ((unsigned long long)(unsigned)(lo + j0 + t) << 42);
        }
    }
}

// ---- Pass 5: one block per fine cell (grid MUST stay 4096: wide
// concurrency of same-bucket cells lets L2 merge scattered out[pos]
// writes; r3 multi-cell variant: 4.4x write amp; r6 no-LDS variant:
// 314MB L2-miss fetch). 17^3 halo via async global_load_lds; 4-pt
// batched payload loads. Pinned ~58us across 4 structural variants. ----
__global__ void __launch_bounds__(GBLK) gather_kernel(
        const float* __restrict__ vol,
        const unsigned long long* __restrict__ payloadF,
        const int* __restrict__ foff, const float* __restrict__ zf,
        float* __restrict__ out) {
    __shared__ float sv[77 * 64];   // 4928 >= 17^3, padded for tail chunk
    const int tid = threadIdx.x;
    const int lane = tid & 63, wv = tid >> 6;
    const int nb = gridDim.x, d = blockIdx.x;
    const int k = (nb % 8 == 0) ? (d % 8) * (nb / 8) + (d / 8) : d;  // XCD swizzle
    const int b = k >> 6;
    const int bz = ((k >> 4) & 3) * 16, by = ((k >> 2) & 3) * 16, bx = (k & 3) * 16;
    const float* vb = vol + ((size_t)b << 18);
    // async halo fill: chunk m covers sv[m*64 .. m*64+63]; wave-uniform LDS base
    for (int m = wv; m < 77; m += GBLK / 64) {
        int l = m * 64 + lane;
        int z = l / 289, r = l - z * 289, y = r / 17, x = r - y * 17;
        int gz = bz + z, gy = by + y, gx = bx + x;
        bool ok = (l < 17 * 17 * 17) && (gz < 64) && (gy < 64) && (gx < 64);
        const float* src = ok ? (vb + ((gz << 12) + (gy << 6) + gx)) : zf;
        __builtin_amdgcn_global_load_lds((const GLOBAL_AS void*)src,
                                         (LDS_AS void*)(sv + m * 64), 4, 0, 0);
    }
    __syncthreads();   // drains vmcnt(0): all async LDS writes landed
    const int lo = foff[k];
    const int n = foff[k + 1] - lo;
    for (int j0 = tid * 4; j0 < n; j0 += GBLK * 4) {
        unsigned long long p[4];
        int m;
        if (j0 + 3 < n) {
            m = 4;
            ulonglong2 a = *(const ulonglong2*)(payloadF + lo + j0);
            ulonglong2 b2 = *(const ulonglong2*)(payloadF + lo + j0 + 2);
            p[0] = a.x; p[1] = a.y; p[2] = b2.x; p[3] = b2.y;
        } else {
            m = n - j0;
            for (int t = 0; t < m; ++t) p[t] = payloadF[lo + j0 + t];
        }
        #pragma unroll 4
        for (int t = 0; t < m; ++t) {
            unsigned long long pp = p[t];
            int qx = (int)(pp & 16383), qy = (int)((pp >> 14) & 16383);
            int qz = (int)((pp >> 28) & 16383);
            int pos = (int)(pp >> 42);
            float wx = (qx & 255) * (1.0f / 256.0f);
            float wy = (qy & 255) * (1.0f / 256.0f);
            float wz = (qz & 255) * (1.0f / 256.0f);
            int lx = (qx >> 8) - bx, ly = (qy >> 8) - by, lz = (qz >> 8) - bz;
            int base = lz * 289 + ly * 17 + lx;
            float v000 = sv[base],       v001 = sv[base + 1];
            float v010 = sv[base + 17],  v011 = sv[base + 18];
            float v100 = sv[base + 289], v101 = sv[base + 290];
            float v110 = sv[base + 306], v111 = sv[base + 307];
            float c00 = v000 + wx * (v001 - v000);
            float c01 = v010 + wx * (v011 - v010);
            float c10 = v100 + wx * (v101 - v100);
            float c11 = v110 + wx * (v111 - v110);
            float c0 = c00 + wy * (c01 - c00);
            float c1 = c10 + wy * (c11 - c10);
            out[pos] = c0 + wz * (c1 - c0);
        }
    }
}

// ---------------- fallback path (N > 2^22 or tiny ws) ----------------
__global__ void fb_hist_kernel(const float* __restrict__ xyz,
                               const float* __restrict__ aabb,
                               int* __restrict__ hist, int N, int G) {
    __shared__ int s_h[NB];
    const int tid = threadIdx.x, g = blockIdx.x;
    if (tid < NB) s_h[tid] = 0;
    __syncthreads();
    const float a0x = aabb[0], a0y = aabb[1], a0z = aabb[2];
    const float vx = (aabb[3] - a0x) * 0.25f;
    const float vy = (aabb[4] - a0y) * 0.25f;
    const float vz = (aabb[5] - a0z) * 0.25f;
    for (int c = 0; c < FB_TILE / 256; ++c) {
        int i = g * FB_TILE + c * 256 + tid;
        if (i < N)
            atomicAdd(&s_h[compute_bid(xyz[3 * i], xyz[3 * i + 1], xyz[3 * i + 2],
                                       a0x, a0y, a0z, vx, vy, vz)], 1);
    }
    __syncthreads();
    if (tid < NB) hist[tid * G + g] = s_h[tid];
}

__global__ void fb_scan_kernel(int* __restrict__ hist, int* __restrict__ tot, int G) {
    __shared__ int sh[SBLK];
    const int b = blockIdx.x, t = threadIdx.x;
    const int L = (G + SBLK - 1) / SBLK;
    const int lo = t * L;
    const int n = min(L, max(0, G - lo));
    const int base = b * G + lo;
    int s = 0;
    for (int k = 0; k < n; ++k) s += hist[base + k];
    sh[t] = s;
    __syncthreads();
    for (int off = 1; off < SBLK; off <<= 1) {
        int v = (t >= off) ? sh[t - off] : 0;
        __syncthreads();
        sh[t] += v;
        __syncthreads();
    }
    int excl = (t == 0) ? 0 : sh[t - 1];
    for (int k = 0; k < n; ++k) {
        int v = hist[base + k];
        hist[base + k] = excl;
        excl += v;
    }
    if (t == SBLK - 1) tot[b] = sh[SBLK - 1];
}

__global__ void fb_scatter_kernel(const float* __restrict__ xyz,
                                  const float* __restrict__ aabb,
                                  const float* __restrict__ dmin,
                                  const float* __restrict__ dmax,
                                  const float* __restrict__ vol,
                                  const int* __restrict__ hist,
                                  const int* __restrict__ tot64,
                                  float* __restrict__ out, int N, int G) {
    __shared__ int   s_cnt[NB], s_off[NB];
    __shared__ int   s_whist[4][NB];
    __shared__ float s_dn[192], s_sc[192];
    const int tid = threadIdx.x, g = blockIdx.x;
    if (tid < NB) s_off[tid] = tot64[tid];
    if (tid < 192) { s_dn[tid] = dmin[tid]; s_sc[tid] = 63.0f / (dmax[tid] - dmin[tid]); }
    __syncthreads();
    for (int o = 1; o < NB; o <<= 1) {
        int v = (tid < NB && tid >= o) ? s_off[tid - o] : 0;
        __syncthreads();
        if (tid < NB) s_off[tid] += v;
        __syncthreads();
    }
    if (tid < NB) s_cnt[tid] = hist[tid * G + g] + (tid ? s_off[tid - 1] : 0);
    const float a0x = aabb[0], a0y = aabb[1], a0z = aabb[2];
    const float vx = (aabb[3] - a0x) * 0.25f;
    const float vy = (aabb[4] - a0y) * 0.25f;
    const float vz = (aabb[5] - a0z) * 0.25f;
    __syncthreads();
    const int lane = tid & 63, wv = tid >> 6;
    const unsigned long long lt = (1ull << lane) - 1ull;
    for (int c = 0; c < FB_TILE / 256; ++c) {
        int i = g * FB_TILE + c * 256 + tid;
        bool valid = (i < N);
        int b = 0;
        float alpha = 0.0f;
        if (valid) {
            float px = xyz[3 * i], py = xyz[3 * i + 1], pz = xyz[3 * i + 2];
            b = compute_bid(px, py, pz, a0x, a0y, a0z, vx, vy, vz);
            float fx = (px - s_dn[3 * b])     * s_sc[3 * b];
            float fy = (py - s_dn[3 * b + 1]) * s_sc[3 * b + 1];
            float fz = (pz - s_dn[3 * b + 2]) * s_sc[3 * b + 2];
            float x0f = floorf(fx), y0f = floorf(fy), z0f = floorf(fz);
            float wx = fx - x0f, wy = fy - y0f, wz = fz - z0f;
            int x0 = (int)x0f, y0 = (int)y0f, z0 = (int)z0f;
            const float* vb = vol + ((size_t)b << 18);
            auto F = [&](int zi, int yi, int xi) -> float {
                if ((unsigned)zi >= 64u || (unsigned)yi >= 64u || (unsigned)xi >= 64u)
                    return 0.0f;
                return vb[(zi << 12) + (yi << 6) + xi];
            };
            float s = 0.0f;
            s += (1.0f - wz) * (1.0f - wy) * (1.0f - wx) * F(z0,     y0,     x0);
            s += (1.0f - wz) * (1.0f - wy) * wx          * F(z0,     y0,     x0 + 1);
            s += (1.0f - wz) * wy          * (1.0f - wx) * F(z0,     y0 + 1, x0);
            s += (1.0f - wz) * wy          * wx          * F(z0,     y0 + 1, x0 + 1);
            s += wz          * (1.0f - wy) * (1.0f - wx) * F(z0 + 1, y0,     x0);
            s += wz          * (1.0f - wy) * wx          * F(z0 + 1, y0,     x0 + 1);
            s += wz          * wy          * (1.0f - wx) * F(z0 + 1, y0 + 1, x0);
            s += wz          * wy          * wx          * F(z0 + 1, y0 + 1, x0 + 1);
            alpha = s;
        }
        ((int*)s_whist)[tid] = 0;
        __syncthreads();
        unsigned long long m = __ballot(valid);
        #pragma unroll
        for (int q = 0; q < 6; ++q) {
            unsigned long long bal = __ballot((b >> q) & 1);
            m &= ((b >> q) & 1) ? bal : ~bal;
        }
        int rank = __popcll(m & lt);
        if (valid && rank == 0) s_whist[wv][b] = __popcll(m);
        __syncthreads();
        if (valid) {
            int pos = s_cnt[b] + rank;
            for (int w2 = 0; w2 < wv; ++w2) pos += s_whist[w2][b];
            out[pos] = alpha;
        }
        __syncthreads();
        if (tid < NB)
            s_cnt[tid] += s_whist[0][tid] + s_whist[1][tid] +
                          s_whist[2][tid] + s_whist[3][tid];
        __syncthreads();
    }
}

extern "C" void kernel_launch(void* const* d_in, const int* in_sizes, int n_in,
                              void* d_out, int out_size, void* d_ws, size_t ws_size,
                              hipStream_t stream) {
    const float* xyz  = (const float*)d_in[0];
    const float* aabb = (const float*)d_in[1];
    const float* vol  = (const float*)d_in[2];
    const float* dmin = (const float*)d_in[3];
    const float* dmax = (const float*)d_in[4];
    float* out = (float*)d_out;
    const int N = in_sizes[0] / 3;
    const int T = (N + TILE - 1) / TILE;

    auto align = [](size_t x) { return (x + 255) & ~(size_t)255; };
    char* ws = (char*)d_ws;
    size_t o = 0;
    unsigned long long* payloadC = (unsigned long long*)(ws + o); o += align((size_t)N * 8);
    unsigned long long* payloadF = (unsigned long long*)(ws + o); o += align((size_t)N * 8);
    int* hist64  = (int*)(ws + o); o += align((size_t)NB * T * 4);
    int* tot64   = (int*)(ws + o); o += 256;
    // contiguous int-scratch region: tot4096 .. zf, zeroed with ONE memset
    size_t zbase = o;
    int* tot4096 = (int*)(ws + o); o += align((size_t)NF * 4);
    int* foff    = (int*)(ws + o); o += align((size_t)(NF + 1) * 4);
    int* fcnt    = (int*)(ws + o); o += align((size_t)NF * 4);
    float* zf    = (float*)(ws + o); o += 256;   // guaranteed-zero word for OOB lanes
    size_t zlen = o - zbase;
    const bool fine = (N <= (1 << 22)) && (ws_size >= o);

    if (fine) {
        hipMemsetAsync(ws + zbase, 0, zlen, stream);
        hist_kernel<<<T, HBLK, 0, stream>>>(xyz, aabb, dmin, dmax,
                                            hist64, tot4096, N, T);
        scans_kernel<<<NB + 1, SBLK, 0, stream>>>(hist64, tot64, tot4096,
                                                  foff, fcnt, T);
        scatterC_kernel<<<T, DBLK, 0, stream>>>(xyz, aabb, dmin, dmax,
                                                hist64, tot64, payloadC, N, T);
        scatterF_kernel<<<T, FBLK, 0, stream>>>(payloadC, fcnt, payloadF, N);
        gather_kernel<<<NF, GBLK, 0, stream>>>(vol, payloadF, foff, zf, out);
    } else {
        const int Gf = (N + FB_TILE - 1) / FB_TILE;
        int* h = (int*)ws;
        int* t = (int*)(ws + align((size_t)NB * Gf * 4));
        fb_hist_kernel<<<Gf, 256, 0, stream>>>(xyz, aabb, h, N, Gf);
        fb_scan_kernel<<<NB, SBLK, 0, stream>>>(h, t, Gf);
        fb_scatter_kernel<<<Gf, 256, 0, stream>>>(xyz, aabb, dmin, dmax, vol,
                                                  h, t, out, N, Gf);
    }
}

// Round 12
// 250.149 us; speedup vs baseline: 1.0945x; 1.0945x over previous
//
#include <hip/hip_runtime.h>

#define NB     64
#define NF     4096
#define TILE   16384
#define HBLK   1024
#define DBLK   1024   // 16 waves
#define FBLK   512
#define GBLK   256
#define SBLK   256
#define FB_TILE 4096
#define STAGE_HALF 8192   // scatterC LDS staging chunk (64 KB)

#define GLOBAL_AS __attribute__((address_space(1)))
#define LDS_AS    __attribute__((address_space(3)))

// bit-exact bid (order-determining — plain divides, matches reference)
__device__ __forceinline__ int compute_bid(float px, float py, float pz,
                                           float a0x, float a0y, float a0z,
                                           float vx, float vy, float vz) {
    int ix = (int)floorf((px - a0x) / vx);
    int iy = (int)floorf((py - a0y) / vy);
    int iz = (int)floorf((pz - a0z) / vz);
    ix = min(max(ix, 0), 3);
    iy = min(max(iy, 0), 3);
    iz = min(max(iz, 0), 3);
    return ix * 16 + iy * 4 + iz;
}

// 14-bit fixed-point (8 frac bits) quantization; IDENTICAL in hist & scatterC.
__device__ __forceinline__ void quant_point(float px, float py, float pz,
        float a0x, float a0y, float a0z, float vx, float vy, float vz,
        const float* s_dn, const float* s_sc,
        int& b, int& qx, int& qy, int& qz, int& key) {
    b = compute_bid(px, py, pz, a0x, a0y, a0z, vx, vy, vz);
    float fx = (px - s_dn[3 * b])     * s_sc[3 * b];
    float fy = (py - s_dn[3 * b + 1]) * s_sc[3 * b + 1];
    float fz = (pz - s_dn[3 * b + 2]) * s_sc[3 * b + 2];
    qx = min(max(__float2int_rn(fx * 256.0f), 0), 16128);
    qy = min(max(__float2int_rn(fy * 256.0f), 0), 16128);
    qz = min(max(__float2int_rn(fz * 256.0f), 0), 16128);
    key = (b << 6) | ((qz >> 12) << 4) | ((qy >> 12) << 2) | (qx >> 12);
}

// ---- Pass 1: coarse per-tile hist (bucket-major) + global fine totals ----
__global__ void __launch_bounds__(HBLK) hist_kernel(
        const float* __restrict__ xyz, const float* __restrict__ aabb,
        const float* __restrict__ dmin, const float* __restrict__ dmax,
        int* __restrict__ hist64, int* __restrict__ tot4096, int N, int T) {
    __shared__ int   sh[NF];
    __shared__ float s_dn[192], s_sc[192];
    const int tid = threadIdx.x, g = blockIdx.x;
    for (int l = tid; l < NF; l += HBLK) sh[l] = 0;
    if (tid < 192) { s_dn[tid] = dmin[tid]; s_sc[tid] = 63.0f / (dmax[tid] - dmin[tid]); }
    const float a0x = aabb[0], a0y = aabb[1], a0z = aabb[2];
    const float vx = (aabb[3] - a0x) * 0.25f;
    const float vy = (aabb[4] - a0y) * 0.25f;
    const float vz = (aabb[5] - a0z) * 0.25f;
    __syncthreads();
    for (int c = 0; c < TILE / (HBLK * 4); ++c) {
        int p0 = g * TILE + c * (HBLK * 4) + tid * 4;
        int b, qx, qy, qz, k;
        if (p0 + 3 < N) {
            const float4* v4 = (const float4*)(xyz + (size_t)p0 * 3);
            float4 f0 = v4[0], f1 = v4[1], f2 = v4[2];
            quant_point(f0.x, f0.y, f0.z, a0x, a0y, a0z, vx, vy, vz, s_dn, s_sc, b, qx, qy, qz, k);
            atomicAdd(&sh[k], 1);
            quant_point(f0.w, f1.x, f1.y, a0x, a0y, a0z, vx, vy, vz, s_dn, s_sc, b, qx, qy, qz, k);
            atomicAdd(&sh[k], 1);
            quant_point(f1.z, f1.w, f2.x, a0x, a0y, a0z, vx, vy, vz, s_dn, s_sc, b, qx, qy, qz, k);
            atomicAdd(&sh[k], 1);
            quant_point(f2.y, f2.z, f2.w, a0x, a0y, a0z, vx, vy, vz, s_dn, s_sc, b, qx, qy, qz, k);
            atomicAdd(&sh[k], 1);
        } else {
            for (int t = 0; t < 4; ++t) {
                int i = p0 + t;
                if (i < N) {
                    quant_point(xyz[3 * i], xyz[3 * i + 1], xyz[3 * i + 2],
                                a0x, a0y, a0z, vx, vy, vz, s_dn, s_sc, b, qx, qy, qz, k);
                    atomicAdd(&sh[k], 1);
                }
            }
        }
    }
    __syncthreads();
    for (int l = tid; l < NF; l += HBLK) {
        int c = sh[l];
        if (c) atomicAdd(&tot4096[l], c);
    }
    if (tid < NB) {
        int s = 0;
        #pragma unroll
        for (int j = 0; j < 64; ++j) s += sh[tid * 64 + j];
        hist64[tid * T + g] = s;
    }
}

// ---- Pass 2: blocks 0..63 scan hist64 rows (in place, + tot64);
//      block 64 scans fine totals -> foff[0..NF], fcnt=foff ----
__global__ void scans_kernel(int* __restrict__ hist64, int* __restrict__ tot64,
                             const int* __restrict__ tot4096,
                             int* __restrict__ foff, int* __restrict__ fcnt, int G) {
    __shared__ int sh[SBLK];
    const int t = threadIdx.x;
    if (blockIdx.x < NB) {
        const int b = blockIdx.x;
        const int L = (G + SBLK - 1) / SBLK;
        const int lo = t * L;
        const int n = min(L, max(0, G - lo));
        const int base = b * G + lo;
        int s = 0;
        for (int k = 0; k < n; ++k) s += hist64[base + k];
        sh[t] = s;
        __syncthreads();
        for (int off = 1; off < SBLK; off <<= 1) {
            int v = (t >= off) ? sh[t - off] : 0;
            __syncthreads();
            sh[t] += v;
            __syncthreads();
        }
        int excl = (t == 0) ? 0 : sh[t - 1];
        for (int k = 0; k < n; ++k) {
            int v = hist64[base + k];
            hist64[base + k] = excl;
            excl += v;
        }
        if (t == SBLK - 1) tot64[b] = sh[SBLK - 1];
    } else {
        const int L = NF / SBLK;  // 16
        int loc[16];
        int s = 0;
        #pragma unroll
        for (int j = 0; j < L; ++j) { loc[j] = tot4096[t * L + j]; s += loc[j]; }
        sh[t] = s;
        __syncthreads();
        for (int o = 1; o < SBLK; o <<= 1) {
            int v = (t >= o) ? sh[t - o] : 0;
            __syncthreads();
            sh[t] += v;
            __syncthreads();
        }
        int run = (t == 0) ? 0 : sh[t - 1];
        #pragma unroll
        for (int j = 0; j < L; ++j) {
            foff[t * L + j] = run;
            fcnt[t * L + j] = run;
            run += loc[j];
        }
        if (t == SBLK - 1) foff[NF] = run;  // == N
    }
}

// ---- Pass 3: COARSE stable scatter — PACKED-RANK variant (r12).
// r11: recompute fixed write-amp (80->33 MB) and regalloc (VGPR 40) but ran
// compute_bid (3 divides) and the 6-ballot rank chain 3x per point -> 73%
// VALUBusy. Fix: pass A packs (b<<10|localpos) = 16 bits/round into 8 VGPRs.
// B-passes unpack -> lidx WITHOUT loading xyz; only lanes whose lidx is in
// the current half load+quant (exec-masked). Divides 3x->1x, ballots 3x->1x,
// payload regs 32->8. Dump pattern (amp ~1) unchanged. ----
__global__ void __launch_bounds__(DBLK) scatterC_kernel(
        const float* __restrict__ xyz, const float* __restrict__ aabb,
        const float* __restrict__ dmin, const float* __restrict__ dmax,
        const int* __restrict__ hist64, const int* __restrict__ tot64,
        unsigned long long* __restrict__ payloadC, int N, int T) {
    __shared__ unsigned long long stage[STAGE_HALF];   // 64 KB staging (half tile)
    __shared__ int   s_wh[16][NB];
    __shared__ int   s_cnt0[NB];
    __shared__ int   s_off[NB];
    __shared__ int   s_start[NB];   // tile-local bucket starts (exclusive)
    __shared__ int   s_gb[NB];      // global base - local start
    __shared__ float s_dn[192], s_sc[192];
    const int tid = threadIdx.x, g = blockIdx.x;
    const int lane = tid & 63, wv = tid >> 6;
    if (tid < NB) s_off[tid] = tot64[tid];
    if (tid < 192) { s_dn[tid] = dmin[tid]; s_sc[tid] = 63.0f / (dmax[tid] - dmin[tid]); }
    ((int*)s_wh)[tid] = 0;   // 16*64 == DBLK
    const float a0x = aabb[0], a0y = aabb[1], a0z = aabb[2];
    const float vx = (aabb[3] - a0x) * 0.25f;
    const float vy = (aabb[4] - a0y) * 0.25f;
    const float vz = (aabb[5] - a0z) * 0.25f;
    __syncthreads();
    for (int o = 1; o < NB; o <<= 1) {
        int v = (tid < NB && tid >= o) ? s_off[tid - o] : 0;
        __syncthreads();
        if (tid < NB) s_off[tid] += v;
        __syncthreads();
    }
    if (tid < NB) s_cnt0[tid] = hist64[tid * T + g] + (tid ? s_off[tid - 1] : 0);

    const unsigned long long lt = (1ull << lane) - 1ull;
    const int base_i = g * TILE + wv * 1024;
    unsigned pk[8] = {0, 0, 0, 0, 0, 0, 0, 0};   // (b<<10|localpos) x16 rounds
    // ---- pass A: bid + stable rank once; pack 16 bits/round ----
    #pragma unroll
    for (int r = 0; r < 16; ++r) {
        int i = base_i + r * 64 + lane;
        bool valid = (i < N);
        int b = 0;
        if (valid) {
            b = compute_bid(xyz[3 * i], xyz[3 * i + 1], xyz[3 * i + 2],
                            a0x, a0y, a0z, vx, vy, vz);
        }
        unsigned long long m = __ballot(valid);
        #pragma unroll
        for (int q = 0; q < 6; ++q) {
            unsigned long long bal = __ballot((b >> q) & 1);
            m &= ((b >> q) & 1) ? bal : ~bal;
        }
        int rank = __popcll(m & lt);
        int run = valid ? s_wh[wv][b] : 0;
        if (valid && rank == 0) s_wh[wv][b] = run + __popcll(m);
        int localpos = valid ? (run + rank) : 0;
        pk[r >> 1] |= (unsigned)((b << 10) | localpos) << ((r & 1) * 16);
    }
    __syncthreads();
    // inclusive scan over the 16 waves
    for (int o = 1; o < 16; o <<= 1) {
        int v = (wv >= o) ? s_wh[wv - o][lane] : 0;
        __syncthreads();
        s_wh[wv][lane] += v;
        __syncthreads();
    }
    // exclusive scan over buckets of tile totals (wave 0, shuffle scan)
    if (wv == 0) {
        int v = s_wh[15][lane];
        int incl = v;
        #pragma unroll
        for (int o = 1; o < 64; o <<= 1) {
            int u = __shfl_up(incl, o);
            if (lane >= o) incl += u;
        }
        int excl = incl - v;
        s_start[lane] = excl;
        s_gb[lane] = s_cnt0[lane] - excl;
    }
    __syncthreads();
    const int n = min(TILE, N - g * TILE);
    // B pass: lidx from cached (b,localpos) — no load, no ballot; only lanes
    // whose lidx is in the current half load xyz (L2-hot) + quant + stage.
    auto passB = [&](int half) {
        #pragma unroll
        for (int r = 0; r < 16; ++r) {
            int i = base_i + r * 64 + lane;
            unsigned val = (pk[r >> 1] >> ((r & 1) * 16)) & 0xFFFFu;
            int b = (int)(val >> 10);
            int localpos = (int)(val & 1023u);
            int lidx = s_start[b] + (wv ? s_wh[wv - 1][b] : 0) + localpos;
            bool doit = (i < N) &&
                        (half == 0 ? (lidx < STAGE_HALF) : (lidx >= STAGE_HALF));
            if (doit) {
                float px = xyz[3 * i], py = xyz[3 * i + 1], pz = xyz[3 * i + 2];
                float fx = (px - s_dn[3 * b])     * s_sc[3 * b];
                float fy = (py - s_dn[3 * b + 1]) * s_sc[3 * b + 1];
                float fz = (pz - s_dn[3 * b + 2]) * s_sc[3 * b + 2];
                int qx = min(max(__float2int_rn(fx * 256.0f), 0), 16128);
                int qy = min(max(__float2int_rn(fy * 256.0f), 0), 16128);
                int qz = min(max(__float2int_rn(fz * 256.0f), 0), 16128);
                unsigned long long p48 =
                      (unsigned long long)(unsigned)qx
                    | ((unsigned long long)(unsigned)qy << 14)
                    | ((unsigned long long)(unsigned)qz << 28)
                    | ((unsigned long long)(unsigned)b  << 42);
                stage[half ? (lidx - STAGE_HALF) : lidx] = p48;
            }
        }
    };
    // ---- B1: stage lidx < STAGE_HALF ----
    passB(0);
    __syncthreads();
    // dump A: j-contiguous reads -> piecewise-contiguous coalesced writes
    {
        int nA = min(n, STAGE_HALF);
        for (int j = tid; j < nA; j += DBLK) {
            unsigned long long p = stage[j];
            int b = (int)((p >> 42) & 63);
            payloadC[s_gb[b] + j] = p;
        }
    }
    __syncthreads();
    // ---- B2: stage lidx >= STAGE_HALF ----
    passB(1);
    __syncthreads();
    // dump B
    for (int j = STAGE_HALF + tid; j < n; j += DBLK) {
        unsigned long long p = stage[j - STAGE_HALF];
        int b = (int)((p >> 42) & 63);
        payloadC[s_gb[b] + j] = p;
    }
}

// ---- Pass 4: FINE scatter, fused hist+reserve+scatter on a contiguous
// coarse-sorted tile. Runs ~256/cell -> 2KB writes (amp ~1).
// 4-point batched loads: one latency exposure per 4 points. ----
__global__ void __launch_bounds__(FBLK) scatterF_kernel(
        const unsigned long long* __restrict__ payloadC,
        int* __restrict__ fcnt,
        unsigned long long* __restrict__ payloadF, int N) {
    __shared__ int s_fb[NF];  // 16 KB
    const int tid = threadIdx.x, t2 = blockIdx.x;
    for (int l = tid; l < NF; l += FBLK) s_fb[l] = 0;
    __syncthreads();
    const int lo = t2 * TILE;
    const int n = min(TILE, N - lo);
    for (int j0 = tid * 4; j0 < n; j0 += FBLK * 4) {
        unsigned long long p[4];
        int m;
        if (j0 + 3 < n) {
            m = 4;
            ulonglong2 a = *(const ulonglong2*)(payloadC + lo + j0);
            ulonglong2 b2 = *(const ulonglong2*)(payloadC + lo + j0 + 2);
            p[0] = a.x; p[1] = a.y; p[2] = b2.x; p[3] = b2.y;
        } else {
            m = n - j0;
            for (int t = 0; t < m; ++t) p[t] = payloadC[lo + j0 + t];
        }
        for (int t = 0; t < m; ++t) {
            unsigned long long pp = p[t];
            int qx = (int)(pp & 16383), qy = (int)((pp >> 14) & 16383);
            int qz = (int)((pp >> 28) & 16383), b = (int)((pp >> 42) & 63);
            int key = (b << 6) | ((qz >> 12) << 4) | ((qy >> 12) << 2) | (qx >> 12);
            atomicAdd(&s_fb[key], 1);
        }
    }
    __syncthreads();
    for (int l = tid; l < NF; l += FBLK) {
        int c = s_fb[l];
        s_fb[l] = c ? atomicAdd(&fcnt[l], c) : 0;   // reserve contiguous range
    }
    __syncthreads();
    for (int j0 = tid * 4; j0 < n; j0 += FBLK * 4) {   // L2-hot re-read
        unsigned long long p[4];
        int m;
        if (j0 + 3 < n) {
            m = 4;
            ulonglong2 a = *(const ulonglong2*)(payloadC + lo + j0);
            ulonglong2 b2 = *(const ulonglong2*)(payloadC + lo + j0 + 2);
            p[0] = a.x; p[1] = a.y; p[2] = b2.x; p[3] = b2.y;
        } else {
            m = n - j0;
            for (int t = 0; t < m; ++t) p[t] = payloadC[lo + j0 + t];
        }
        for (int t = 0; t < m; ++t) {
            unsigned long long pp = p[t];
            int qx = (int)(pp & 16383), qy = (int)((pp >> 14) & 16383);
            int qz = (int)((pp >> 28) & 16383), b = (int)((pp >> 42) & 63);
            int key = (b << 6) | ((qz >> 12) << 4) | ((qy >> 12) << 2) | (qx >> 12);
            int fpos = atomicAdd(&s_fb[key], 1);
            payloadF[fpos] = (pp & ((1ull << 42) - 1))
                           | ((unsigned long long)(unsigned)(lo + j0 + t) << 42);
        }
    }
}

// ---- Pass 5: one block per fine cell (grid MUST stay 4096: wide
// concurrency of same-bucket cells lets L2 merge scattered out[pos]
// writes; r3 multi-cell variant: 4.4x write amp; r6 no-LDS variant:
// 314MB L2-miss fetch). 17^3 halo via async global_load_lds; 4-pt
// batched payload loads. Pinned ~58us across 4 structural variants. ----
__global__ void __launch_bounds__(GBLK) gather_kernel(
        const float* __restrict__ vol,
        const unsigned long long* __restrict__ payloadF,
        const int* __restrict__ foff, const float* __restrict__ zf,
        float* __restrict__ out) {
    __shared__ float sv[77 * 64];   // 4928 >= 17^3, padded for tail chunk
    const int tid = threadIdx.x;
    const int lane = tid & 63, wv = tid >> 6;
    const int nb = gridDim.x, d = blockIdx.x;
    const int k = (nb % 8 == 0) ? (d % 8) * (nb / 8) + (d / 8) : d;  // XCD swizzle
    const int b = k >> 6;
    const int bz = ((k >> 4) & 3) * 16, by = ((k >> 2) & 3) * 16, bx = (k & 3) * 16;
    const float* vb = vol + ((size_t)b << 18);
    // async halo fill: chunk m covers sv[m*64 .. m*64+63]; wave-uniform LDS base
    for (int m = wv; m < 77; m += GBLK / 64) {
        int l = m * 64 + lane;
        int z = l / 289, r = l - z * 289, y = r / 17, x = r - y * 17;
        int gz = bz + z, gy = by + y, gx = bx + x;
        bool ok = (l < 17 * 17 * 17) && (gz < 64) && (gy < 64) && (gx < 64);
        const float* src = ok ? (vb + ((gz << 12) + (gy << 6) + gx)) : zf;
        __builtin_amdgcn_global_load_lds((const GLOBAL_AS void*)src,
                                         (LDS_AS void*)(sv + m * 64), 4, 0, 0);
    }
    __syncthreads();   // drains vmcnt(0): all async LDS writes landed
    const int lo = foff[k];
    const int n = foff[k + 1] - lo;
    for (int j0 = tid * 4; j0 < n; j0 += GBLK * 4) {
        unsigned long long p[4];
        int m;
        if (j0 + 3 < n) {
            m = 4;
            ulonglong2 a = *(const ulonglong2*)(payloadF + lo + j0);
            ulonglong2 b2 = *(const ulonglong2*)(payloadF + lo + j0 + 2);
            p[0] = a.x; p[1] = a.y; p[2] = b2.x; p[3] = b2.y;
        } else {
            m = n - j0;
            for (int t = 0; t < m; ++t) p[t] = payloadF[lo + j0 + t];
        }
        #pragma unroll 4
        for (int t = 0; t < m; ++t) {
            unsigned long long pp = p[t];
            int qx = (int)(pp & 16383), qy = (int)((pp >> 14) & 16383);
            int qz = (int)((pp >> 28) & 16383);
            int pos = (int)(pp >> 42);
            float wx = (qx & 255) * (1.0f / 256.0f);
            float wy = (qy & 255) * (1.0f / 256.0f);
            float wz = (qz & 255) * (1.0f / 256.0f);
            int lx = (qx >> 8) - bx, ly = (qy >> 8) - by, lz = (qz >> 8) - bz;
            int base = lz * 289 + ly * 17 + lx;
            float v000 = sv[base],       v001 = sv[base + 1];
            float v010 = sv[base + 17],  v011 = sv[base + 18];
            float v100 = sv[base + 289], v101 = sv[base + 290];
            float v110 = sv[base + 306], v111 = sv[base + 307];
            float c00 = v000 + wx * (v001 - v000);
            float c01 = v010 + wx * (v011 - v010);
            float c10 = v100 + wx * (v101 - v100);
            float c11 = v110 + wx * (v111 - v110);
            float c0 = c00 + wy * (c01 - c00);
            float c1 = c10 + wy * (c11 - c10);
            out[pos] = c0 + wz * (c1 - c0);
        }
    }
}

// ---------------- fallback path (N > 2^22 or tiny ws) ----------------
__global__ void fb_hist_kernel(const float* __restrict__ xyz,
                               const float* __restrict__ aabb,
                               int* __restrict__ hist, int N, int G) {
    __shared__ int s_h[NB];
    const int tid = threadIdx.x, g = blockIdx.x;
    if (tid < NB) s_h[tid] = 0;
    __syncthreads();
    const float a0x = aabb[0], a0y = aabb[1], a0z = aabb[2];
    const float vx = (aabb[3] - a0x) * 0.25f;
    const float vy = (aabb[4] - a0y) * 0.25f;
    const float vz = (aabb[5] - a0z) * 0.25f;
    for (int c = 0; c < FB_TILE / 256; ++c) {
        int i = g * FB_TILE + c * 256 + tid;
        if (i < N)
            atomicAdd(&s_h[compute_bid(xyz[3 * i], xyz[3 * i + 1], xyz[3 * i + 2],
                                       a0x, a0y, a0z, vx, vy, vz)], 1);
    }
    __syncthreads();
    if (tid < NB) hist[tid * G + g] = s_h[tid];
}

__global__ void fb_scan_kernel(int* __restrict__ hist, int* __restrict__ tot, int G) {
    __shared__ int sh[SBLK];
    const int b = blockIdx.x, t = threadIdx.x;
    const int L = (G + SBLK - 1) / SBLK;
    const int lo = t * L;
    const int n = min(L, max(0, G - lo));
    const int base = b * G + lo;
    int s = 0;
    for (int k = 0; k < n; ++k) s += hist[base + k];
    sh[t] = s;
    __syncthreads();
    for (int off = 1; off < SBLK; off <<= 1) {
        int v = (t >= off) ? sh[t - off] : 0;
        __syncthreads();
        sh[t] += v;
        __syncthreads();
    }
    int excl = (t == 0) ? 0 : sh[t - 1];
    for (int k = 0; k < n; ++k) {
        int v = hist[base + k];
        hist[base + k] = excl;
        excl += v;
    }
    if (t == SBLK - 1) tot[b] = sh[SBLK - 1];
}

__global__ void fb_scatter_kernel(const float* __restrict__ xyz,
                                  const float* __restrict__ aabb,
                                  const float* __restrict__ dmin,
                                  const float* __restrict__ dmax,
                                  const float* __restrict__ vol,
                                  const int* __restrict__ hist,
                                  const int* __restrict__ tot64,
                                  float* __restrict__ out, int N, int G) {
    __shared__ int   s_cnt[NB], s_off[NB];
    __shared__ int   s_whist[4][NB];
    __shared__ float s_dn[192], s_sc[192];
    const int tid = threadIdx.x, g = blockIdx.x;
    if (tid < NB) s_off[tid] = tot64[tid];
    if (tid < 192) { s_dn[tid] = dmin[tid]; s_sc[tid] = 63.0f / (dmax[tid] - dmin[tid]); }
    __syncthreads();
    for (int o = 1; o < NB; o <<= 1) {
        int v = (tid < NB && tid >= o) ? s_off[tid - o] : 0;
        __syncthreads();
        if (tid < NB) s_off[tid] += v;
        __syncthreads();
    }
    if (tid < NB) s_cnt[tid] = hist[tid * G + g] + (tid ? s_off[tid - 1] : 0);
    const float a0x = aabb[0], a0y = aabb[1], a0z = aabb[2];
    const float vx = (aabb[3] - a0x) * 0.25f;
    const float vy = (aabb[4] - a0y) * 0.25f;
    const float vz = (aabb[5] - a0z) * 0.25f;
    __syncthreads();
    const int lane = tid & 63, wv = tid >> 6;
    const unsigned long long lt = (1ull << lane) - 1ull;
    for (int c = 0; c < FB_TILE / 256; ++c) {
        int i = g * FB_TILE + c * 256 + tid;
        bool valid = (i < N);
        int b = 0;
        float alpha = 0.0f;
        if (valid) {
            float px = xyz[3 * i], py = xyz[3 * i + 1], pz = xyz[3 * i + 2];
            b = compute_bid(px, py, pz, a0x, a0y, a0z, vx, vy, vz);
            float fx = (px - s_dn[3 * b])     * s_sc[3 * b];
            float fy = (py - s_dn[3 * b + 1]) * s_sc[3 * b + 1];
            float fz = (pz - s_dn[3 * b + 2]) * s_sc[3 * b + 2];
            float x0f = floorf(fx), y0f = floorf(fy), z0f = floorf(fz);
            float wx = fx - x0f, wy = fy - y0f, wz = fz - z0f;
            int x0 = (int)x0f, y0 = (int)y0f, z0 = (int)z0f;
            const float* vb = vol + ((size_t)b << 18);
            auto F = [&](int zi, int yi, int xi) -> float {
                if ((unsigned)zi >= 64u || (unsigned)yi >= 64u || (unsigned)xi >= 64u)
                    return 0.0f;
                return vb[(zi << 12) + (yi << 6) + xi];
            };
            float s = 0.0f;
            s += (1.0f - wz) * (1.0f - wy) * (1.0f - wx) * F(z0,     y0,     x0);
            s += (1.0f - wz) * (1.0f - wy) * wx          * F(z0,     y0,     x0 + 1);
            s += (1.0f - wz) * wy          * (1.0f - wx) * F(z0,     y0 + 1, x0);
            s += (1.0f - wz) * wy          * wx          * F(z0,     y0 + 1, x0 + 1);
            s += wz          * (1.0f - wy) * (1.0f - wx) * F(z0 + 1, y0,     x0);
            s += wz          * (1.0f - wy) * wx          * F(z0 + 1, y0,     x0 + 1);
            s += wz          * wy          * (1.0f - wx) * F(z0 + 1, y0 + 1, x0);
            s += wz          * wy          * wx          * F(z0 + 1, y0 + 1, x0 + 1);
            alpha = s;
        }
        ((int*)s_whist)[tid] = 0;
        __syncthreads();
        unsigned long long m = __ballot(valid);
        #pragma unroll
        for (int q = 0; q < 6; ++q) {
            unsigned long long bal = __ballot((b >> q) & 1);
            m &= ((b >> q) & 1) ? bal : ~bal;
        }
        int rank = __popcll(m & lt);
        if (valid && rank == 0) s_whist[wv][b] = __popcll(m);
        __syncthreads();
        if (valid) {
            int pos = s_cnt[b] + rank;
            for (int w2 = 0; w2 < wv; ++w2) pos += s_whist[w2][b];
            out[pos] = alpha;
        }
        __syncthreads();
        if (tid < NB)
            s_cnt[tid] += s_whist[0][tid] + s_whist[1][tid] +
                          s_whist[2][tid] + s_whist[3][tid];
        __syncthreads();
    }
}

extern "C" void kernel_launch(void* const* d_in, const int* in_sizes, int n_in,
                              void* d_out, int out_size, void* d_ws, size_t ws_size,
                              hipStream_t stream) {
    const float* xyz  = (const float*)d_in[0];
    const float* aabb = (const float*)d_in[1];
    const float* vol  = (const float*)d_in[2];
    const float* dmin = (const float*)d_in[3];
    const float* dmax = (const float*)d_in[4];
    float* out = (float*)d_out;
    const int N = in_sizes[0] / 3;
    const int T = (N + TILE - 1) / TILE;

    auto align = [](size_t x) { return (x + 255) & ~(size_t)255; };
    char* ws = (char*)d_ws;
    size_t o = 0;
    unsigned long long* payloadC = (unsigned long long*)(ws + o); o += align((size_t)N * 8);
    unsigned long long* payloadF = (unsigned long long*)(ws + o); o += align((size_t)N * 8);
    int* hist64  = (int*)(ws + o); o += align((size_t)NB * T * 4);
    int* tot64   = (int*)(ws + o); o += 256;
    // contiguous int-scratch region: tot4096 .. zf, zeroed with ONE memset
    size_t zbase = o;
    int* tot4096 = (int*)(ws + o); o += align((size_t)NF * 4);
    int* foff    = (int*)(ws + o); o += align((size_t)(NF + 1) * 4);
    int* fcnt    = (int*)(ws + o); o += align((size_t)NF * 4);
    float* zf    = (float*)(ws + o); o += 256;   // guaranteed-zero word for OOB lanes
    size_t zlen = o - zbase;
    const bool fine = (N <= (1 << 22)) && (ws_size >= o);

    if (fine) {
        hipMemsetAsync(ws + zbase, 0, zlen, stream);
        hist_kernel<<<T, HBLK, 0, stream>>>(xyz, aabb, dmin, dmax,
                                            hist64, tot4096, N, T);
        scans_kernel<<<NB + 1, SBLK, 0, stream>>>(hist64, tot64, tot4096,
                                                  foff, fcnt, T);
        scatterC_kernel<<<T, DBLK, 0, stream>>>(xyz, aabb, dmin, dmax,
                                                hist64, tot64, payloadC, N, T);
        scatterF_kernel<<<T, FBLK, 0, stream>>>(payloadC, fcnt, payloadF, N);
        gather_kernel<<<NF, GBLK, 0, stream>>>(vol, payloadF, foff, zf, out);
    } else {
        const int Gf = (N + FB_TILE - 1) / FB_TILE;
        int* h = (int*)ws;
        int* t = (int*)(ws + align((size_t)NB * Gf * 4));
        fb_hist_kernel<<<Gf, 256, 0, stream>>>(xyz, aabb, h, N, Gf);
        fb_scan_kernel<<<NB, SBLK, 0, stream>>>(h, t, Gf);
        fb_scatter_kernel<<<Gf, 256, 0, stream>>>(xyz, aabb, dmin, dmax, vol,
                                                  h, t, out, N, Gf);
    }
}